// Round 1
// baseline (421.752 us; speedup 1.0000x reference)
//
#include <hip/hip_runtime.h>
#include <math.h>

#define D_MODEL 256
#define NHEADS 8
#define HDIM 32
#define BATCH 8
#define SEQL 4096
#define EPS 1e-6f

// elu(x)+1 with alpha=1: x>0 ? x+1 : exp(x)
__device__ __forceinline__ float elu1(float x) {
    return x > 0.f ? x + 1.f : __expf(x);
}

// ---------------------------------------------------------------------------
// Projection GEMM: C[b][o][l] = sum_i W[o][i] * X[b][i][l] + bias[o]
// grid (SEQL/64, D_MODEL/64, BATCH), block 256 (16x16 threads, 4x4 microtile)
// ---------------------------------------------------------------------------
__global__ __launch_bounds__(256) void proj_gemm_kernel(
    const float* __restrict__ X, const float* __restrict__ W,
    const float* __restrict__ bias, float* __restrict__ C) {
    __shared__ float As[16][64];  // [k][m]
    __shared__ float Bs[16][64];  // [k][n]
    const int b  = blockIdx.z;
    const int m0 = blockIdx.y * 64;
    const int n0 = blockIdx.x * 64;
    const float* Xb = X + (size_t)b * D_MODEL * SEQL;
    float*       Cb = C + (size_t)b * D_MODEL * SEQL;
    const int tid = threadIdx.x;
    const int tx = tid & 15;   // n-group
    const int ty = tid >> 4;   // m-group
    float acc[4][4] = {};
    for (int k0 = 0; k0 < D_MODEL; k0 += 16) {
        __syncthreads();
        {   // A tile: W[m0..m0+64)[k0..k0+16) -> As[k][m] (transposed store)
            const int r  = tid >> 2;        // 0..63
            const int c4 = (tid & 3) << 2;  // 0,4,8,12
            float4 a = *(const float4*)(W + (size_t)(m0 + r) * D_MODEL + k0 + c4);
            As[c4 + 0][r] = a.x;
            As[c4 + 1][r] = a.y;
            As[c4 + 2][r] = a.z;
            As[c4 + 3][r] = a.w;
        }
        {   // B tile: X[k0..k0+16)[n0..n0+64) -> Bs[k][n]
            const int r  = tid >> 4;         // 0..15
            const int c4 = (tid & 15) << 2;  // 0..60
            *(float4*)&Bs[r][c4] =
                *(const float4*)(Xb + (size_t)(k0 + r) * SEQL + n0 + c4);
        }
        __syncthreads();
#pragma unroll
        for (int k = 0; k < 16; ++k) {
            float4 av = *(const float4*)&As[k][ty << 2];
            float4 bv = *(const float4*)&Bs[k][tx << 2];
            float am[4] = {av.x, av.y, av.z, av.w};
            float bn[4] = {bv.x, bv.y, bv.z, bv.w};
#pragma unroll
            for (int m = 0; m < 4; ++m)
#pragma unroll
                for (int n = 0; n < 4; ++n)
                    acc[m][n] += am[m] * bn[n];
        }
    }
#pragma unroll
    for (int m = 0; m < 4; ++m) {
        const int o = m0 + (ty << 2) + m;
        const float bb = bias[o];
        float4 r;
        r.x = acc[m][0] + bb;
        r.y = acc[m][1] + bb;
        r.z = acc[m][2] + bb;
        r.w = acc[m][3] + bb;
        *(float4*)(Cb + (size_t)o * SEQL + n0 + (tx << 2)) = r;
    }
}

// ---------------------------------------------------------------------------
// Zero-init for KV/ksum accumulators (ws is poisoned 0xAA each launch)
// ---------------------------------------------------------------------------
__global__ void zero_kernel(float* __restrict__ p, int n) {
    int i = blockIdx.x * blockDim.x + threadIdx.x;
    if (i < n) p[i] = 0.f;
}

// ---------------------------------------------------------------------------
// KV[b][h][qd][kd] = sum_l elu1(kp[b][kd*8+h][l]) * vp[b][qd*8+h][l]   (raw, no /L)
// ksum[b][h][kd]   = sum_l elu1(kp[b][kd*8+h][l])
// grid (BATCH*NHEADS, KV_SPLITS), block 256; atomicAdd partials.
// ---------------------------------------------------------------------------
#define KV_SPLITS 8
#define KV_CHUNK 32
__global__ __launch_bounds__(256) void kv_kernel(
    const float* __restrict__ kp, const float* __restrict__ vp,
    float* __restrict__ KV, float* __restrict__ ksum) {
    const int bh = blockIdx.x;
    const int b = bh >> 3;
    const int h = bh & 7;
    const int lbase = blockIdx.y * (SEQL / KV_SPLITS);
    __shared__ float ks[KV_CHUNK][HDIM + 1];  // [l][kd], +1 pad
    __shared__ float vs[KV_CHUNK][HDIM + 1];  // [l][qd]
    const int t  = threadIdx.x;
    const int kd = t & 31;
    const int qg = t >> 5;  // 0..7 -> qd = qg*4 + j
    float acc0 = 0.f, acc1 = 0.f, acc2 = 0.f, acc3 = 0.f;
    float ksacc = 0.f;
    const int cload = t >> 3;       // 0..31 (within-head channel)
    const int l4    = (t & 7) << 2; // 0..28
    const float* kbase = kp + ((size_t)b * D_MODEL + cload * NHEADS + h) * SEQL;
    const float* vbase = vp + ((size_t)b * D_MODEL + cload * NHEADS + h) * SEQL;
    for (int lc = lbase; lc < lbase + SEQL / KV_SPLITS; lc += KV_CHUNK) {
        __syncthreads();
        {
            float4 kq = *(const float4*)(kbase + lc + l4);
            ks[l4 + 0][cload] = elu1(kq.x);
            ks[l4 + 1][cload] = elu1(kq.y);
            ks[l4 + 2][cload] = elu1(kq.z);
            ks[l4 + 3][cload] = elu1(kq.w);
            float4 vq = *(const float4*)(vbase + lc + l4);
            vs[l4 + 0][cload] = vq.x;
            vs[l4 + 1][cload] = vq.y;
            vs[l4 + 2][cload] = vq.z;
            vs[l4 + 3][cload] = vq.w;
        }
        __syncthreads();
#pragma unroll
        for (int li = 0; li < KV_CHUNK; ++li) {
            const float kk = ks[li][kd];
            ksacc += kk;
            acc0 += kk * vs[li][(qg << 2) + 0];
            acc1 += kk * vs[li][(qg << 2) + 1];
            acc2 += kk * vs[li][(qg << 2) + 2];
            acc3 += kk * vs[li][(qg << 2) + 3];
        }
    }
    float* KVb = KV + (size_t)(b * NHEADS + h) * HDIM * HDIM;
    atomicAdd(&KVb[((qg << 2) + 0) * HDIM + kd], acc0);
    atomicAdd(&KVb[((qg << 2) + 1) * HDIM + kd], acc1);
    atomicAdd(&KVb[((qg << 2) + 2) * HDIM + kd], acc2);
    atomicAdd(&KVb[((qg << 2) + 3) * HDIM + kd], acc3);
    if (qg == 0) atomicAdd(&ksum[(size_t)(b * NHEADS + h) * HDIM + kd], ksacc);
}

// ---------------------------------------------------------------------------
// x[b][qd*8+h][l] = sum_kd q'[kd]*KV[b][h][qd][kd] / (sum_kd q'[kd]*ksum[..] + eps)
// where q' = elu1(qp[b][kd*8+h][l]).
// grid (SEQL/64, BATCH), block 256 (thread t owns channel c = t).
// ---------------------------------------------------------------------------
#define LT 64
__global__ __launch_bounds__(256) void attn_kernel(
    const float* __restrict__ qp, const float* __restrict__ KV,
    const float* __restrict__ ksum, float* __restrict__ xout) {
    const int b  = blockIdx.y;
    const int l0 = blockIdx.x * LT;
    const int t  = threadIdx.x;
    __shared__ float qls[LT][D_MODEL + 1];  // [l][c], 65792 B
    const int h  = t & 7;
    const int qd = t >> 3;
    // KV row + ksum row for this thread's (h, qd) into registers
    float kvr[HDIM], ksr[HDIM];
    {
        const float* kvp = KV + ((size_t)(b * NHEADS + h) * HDIM + qd) * HDIM;
        const float* ksp = ksum + (size_t)(b * NHEADS + h) * HDIM;
#pragma unroll
        for (int i = 0; i < HDIM; i += 4) {
            float4 a = *(const float4*)(kvp + i);
            kvr[i + 0] = a.x; kvr[i + 1] = a.y; kvr[i + 2] = a.z; kvr[i + 3] = a.w;
            float4 s = *(const float4*)(ksp + i);
            ksr[i + 0] = s.x; ksr[i + 1] = s.y; ksr[i + 2] = s.z; ksr[i + 3] = s.w;
        }
    }
    // Stage q' tile [l][c] (coalesced along l, elu applied on the way in)
    const int cl  = t >> 4;         // 0..15
    const int ll4 = (t & 15) << 2;  // 0..60
    for (int cc = 0; cc < D_MODEL; cc += 16) {
        const int c = cc + cl;
        float4 qv = *(const float4*)(qp + ((size_t)b * D_MODEL + c) * SEQL + l0 + ll4);
        qls[ll4 + 0][c] = elu1(qv.x);
        qls[ll4 + 1][c] = elu1(qv.y);
        qls[ll4 + 2][c] = elu1(qv.z);
        qls[ll4 + 3][c] = elu1(qv.w);
    }
    __syncthreads();
    // Compute in groups of 8 l, write results back into qls in place
    for (int g = 0; g < LT; g += 8) {
        float num[8] = {}, den[8] = {};
#pragma unroll
        for (int kd = 0; kd < HDIM; ++kd) {
            const float kvv = kvr[kd];
            const float ksv = ksr[kd];
#pragma unroll
            for (int j = 0; j < 8; ++j) {
                const float qk = qls[g + j][kd * NHEADS + h];
                num[j] += qk * kvv;
                den[j] += qk * ksv;
            }
        }
        __syncthreads();  // all reads of rows g..g+7 done before overwriting
#pragma unroll
        for (int j = 0; j < 8; ++j)
            qls[g + j][t] = num[j] / (den[j] + EPS);
    }
    __syncthreads();
    // Store x tile (coalesced along l)
    float* xb = xout + (size_t)b * D_MODEL * SEQL + l0;
    for (int cc = 0; cc < D_MODEL; cc += 16) {
        const int c = cc + cl;
        float4 r;
        r.x = qls[ll4 + 0][c];
        r.y = qls[ll4 + 1][c];
        r.z = qls[ll4 + 2][c];
        r.w = qls[ll4 + 3][c];
        *(float4*)(xb + (size_t)c * SEQL + ll4) = r;
    }
}

// ---------------------------------------------------------------------------
extern "C" void kernel_launch(void* const* d_in, const int* in_sizes, int n_in,
                              void* d_out, int out_size, void* d_ws, size_t ws_size,
                              hipStream_t stream) {
    const float* query = (const float*)d_in[0];
    const float* key_  = (const float*)d_in[1];
    const float* value = (const float*)d_in[2];
    const float* Wq = (const float*)d_in[3];
    const float* bq = (const float*)d_in[4];
    const float* Wk = (const float*)d_in[5];
    const float* bk = (const float*)d_in[6];
    const float* Wv = (const float*)d_in[7];
    const float* bv = (const float*)d_in[8];
    const float* Wm = (const float*)d_in[9];
    const float* bm = (const float*)d_in[10];

    float* ws = (float*)d_ws;
    const size_t NB = (size_t)BATCH * D_MODEL * SEQL;  // 8,388,608 floats
    float* qp   = ws;
    float* kp   = ws + NB;
    float* vp   = ws + 2 * NB;
    float* KV   = ws + 3 * NB;                          // B*H*32*32 floats
    float* ksum = KV + BATCH * NHEADS * HDIM * HDIM;    // B*H*32 floats
    float* xbuf = kp;  // kp dead after kv_kernel; reuse for attention output

    dim3 gproj(SEQL / 64, D_MODEL / 64, BATCH);
    proj_gemm_kernel<<<gproj, 256, 0, stream>>>(query, Wq, bq, qp);
    proj_gemm_kernel<<<gproj, 256, 0, stream>>>(key_,  Wk, bk, kp);
    proj_gemm_kernel<<<gproj, 256, 0, stream>>>(value, Wv, bv, vp);

    const int nz = BATCH * NHEADS * HDIM * HDIM + BATCH * NHEADS * HDIM;
    zero_kernel<<<(nz + 255) / 256, 256, 0, stream>>>(KV, nz);

    kv_kernel<<<dim3(BATCH * NHEADS, KV_SPLITS), 256, 0, stream>>>(kp, vp, KV, ksum);

    attn_kernel<<<dim3(SEQL / LT, BATCH), 256, 0, stream>>>(qp, KV, ksum, xbuf);

    proj_gemm_kernel<<<gproj, 256, 0, stream>>>(xbuf, Wm, bm, (float*)d_out);
}

// Round 2
// 251.304 us; speedup vs baseline: 1.6783x; 1.6783x over previous
//
#include <hip/hip_runtime.h>
#include <math.h>

#define D_MODEL 256
#define NHEADS 8
#define HDIM 32
#define BATCH 8
#define SEQL 4096
#define EPS 1e-6f

typedef _Float16 f16;
typedef _Float16 f16x4 __attribute__((ext_vector_type(4)));
typedef _Float16 f16x8 __attribute__((ext_vector_type(8)));
typedef float f32x4 __attribute__((ext_vector_type(4)));

__device__ __forceinline__ float elu1(float x) {
    return x > 0.f ? x + 1.f : __expf(x);
}

__device__ __forceinline__ void gload_lds16(const void* g, void* l) {
    __builtin_amdgcn_global_load_lds(
        (const __attribute__((address_space(1))) unsigned int*)g,
        (__attribute__((address_space(3))) unsigned int*)l, 16, 0, 0);
}

// ---------------------------------------------------------------------------
// prep: convert 4 weight mats to fp16.  Stage-1 weights row-permuted to
// head-major output channels (o' = h*32+kd <- o = kd*8+h); Wm column-permuted
// to accept head-major input.  Also permute stage-1 biases (kept fp32).
// ---------------------------------------------------------------------------
__global__ void prep_kernel(const float* __restrict__ Wq, const float* __restrict__ Wk,
                            const float* __restrict__ Wv, const float* __restrict__ Wm,
                            const float* __restrict__ bq, const float* __restrict__ bk,
                            const float* __restrict__ bv,
                            f16* __restrict__ w16, float* __restrict__ bperm) {
    if (blockIdx.x < 1024) {
        int idx = blockIdx.x * 256 + threadIdx.x;
        int mat = idx >> 16, r = (idx >> 8) & 255, c = idx & 255;
        const float* W = (mat == 0) ? Wq : (mat == 1) ? Wk : (mat == 2) ? Wv : Wm;
        float v;
        if (mat < 3) v = W[(size_t)(((r & 31) << 3) + (r >> 5)) * 256 + c];
        else         v = W[(size_t)r * 256 + (((c & 31) << 3) + (c >> 5))];
        w16[idx] = (f16)v;
    } else {
        int t = threadIdx.x;
        bperm[0 * 256 + t] = bq[((t & 31) << 3) + (t >> 5)];
        bperm[1 * 256 + t] = bk[((t & 31) << 3) + (t >> 5)];
        bperm[2 * 256 + t] = bv[((t & 31) << 3) + (t >> 5)];
    }
}

__global__ void zero_kernel(float* __restrict__ p, int n) {
    int i = blockIdx.x * blockDim.x + threadIdx.x;
    if (i < n) p[i] = 0.f;
}

// ---------------------------------------------------------------------------
// Stage-1 GEMM: Y[b][l][o'] = fp16( sum_i W16[o'][i] * X[b][i][l] + bperm[o'] )
// M=o' (128-tile, grid.y=2), N=l (128-tile, grid.x=32), K=i=256, BK=32.
// grid.z = 24: which = z>>3 (q/k/v), b = z&7.  256 threads, 4 waves in 2x2.
// ---------------------------------------------------------------------------
#define BSTR 40  // Bs row stride in halves (16B-aligned rows, 2-way banks)
__global__ __launch_bounds__(256) void gemm_stage1(
    const float* __restrict__ Xq, const float* __restrict__ Xk, const float* __restrict__ Xv,
    const f16* __restrict__ w16, const float* __restrict__ bperm,
    f16* __restrict__ yq, f16* __restrict__ yk, f16* __restrict__ yv) {
    __shared__ __align__(16) char smem[18432];
    f16* As = (f16*)smem;            // [128][32]
    f16* Bs = (f16*)(smem + 8192);   // [128][BSTR]
    f16* Cb = (f16*)smem;            // [128][72] epilogue bounce (aliases)

    const int z = blockIdx.z;
    const int which = z >> 3;
    const int b = z & 7;
    const float* X = (which == 0) ? Xq : (which == 1) ? Xk : Xv;
    const f16* W = w16 + which * 65536;
    f16* Y = (which == 0) ? yq : (which == 1) ? yk : yv;
    const float* bp = bperm + which * 256;

    const int l0 = blockIdx.x * 128;
    const int m0 = blockIdx.y * 128;
    const int tid = threadIdx.x;
    const int wave = tid >> 6, lane = tid & 63;
    const int wm = wave >> 1, wn = wave & 1;
    const int ln = lane & 15, quad = lane >> 4;
    // B staging coords
    const int bp8 = tid & 7;    // i-quad: i_local = 4*bp8 + r
    const int bg = tid >> 3;    // l-quad: l_local = 4*bg + j

    f32x4 acc[4][4];
#pragma unroll
    for (int mf = 0; mf < 4; ++mf)
#pragma unroll
        for (int nf = 0; nf < 4; ++nf)
#pragma unroll
            for (int r = 0; r < 4; ++r) acc[mf][nf][r] = 0.f;

    for (int k0 = 0; k0 < D_MODEL; k0 += 32) {
        __syncthreads();
        // A tile: 128x32 fp16, async direct to LDS (2 issues/wave)
#pragma unroll
        for (int iss = 0; iss < 2; ++iss) {
            const int row = wave * 32 + iss * 16 + (lane >> 2);
            const f16* gp = W + (size_t)(m0 + row) * 256 + k0 + (lane & 3) * 8;
            gload_lds16(gp, As + (wave * 32 + iss * 16) * 32);
        }
        // B tile: X[k0+i][l0+l] fp32 -> transpose/convert -> Bs[l][i]
        {
            const float* xb = X + ((size_t)b * D_MODEL + k0 + 4 * bp8) * SEQL + l0 + 4 * bg;
            float4 r0 = *(const float4*)(xb + 0 * SEQL);
            float4 r1 = *(const float4*)(xb + 1 * SEQL);
            float4 r2 = *(const float4*)(xb + 2 * SEQL);
            float4 r3 = *(const float4*)(xb + 3 * SEQL);
            f16x4 w;
            w[0] = (f16)r0.x; w[1] = (f16)r1.x; w[2] = (f16)r2.x; w[3] = (f16)r3.x;
            *(f16x4*)&Bs[(4 * bg + 0) * BSTR + 4 * bp8] = w;
            w[0] = (f16)r0.y; w[1] = (f16)r1.y; w[2] = (f16)r2.y; w[3] = (f16)r3.y;
            *(f16x4*)&Bs[(4 * bg + 1) * BSTR + 4 * bp8] = w;
            w[0] = (f16)r0.z; w[1] = (f16)r1.z; w[2] = (f16)r2.z; w[3] = (f16)r3.z;
            *(f16x4*)&Bs[(4 * bg + 2) * BSTR + 4 * bp8] = w;
            w[0] = (f16)r0.w; w[1] = (f16)r1.w; w[2] = (f16)r2.w; w[3] = (f16)r3.w;
            *(f16x4*)&Bs[(4 * bg + 3) * BSTR + 4 * bp8] = w;
        }
        __syncthreads();
        f16x8 af[4], bf[4];
#pragma unroll
        for (int mf = 0; mf < 4; ++mf)
            af[mf] = *(const f16x8*)&As[(wm * 64 + mf * 16 + ln) * 32 + quad * 8];
#pragma unroll
        for (int nf = 0; nf < 4; ++nf)
            bf[nf] = *(const f16x8*)&Bs[(wn * 64 + nf * 16 + ln) * BSTR + quad * 8];
#pragma unroll
        for (int mf = 0; mf < 4; ++mf)
#pragma unroll
            for (int nf = 0; nf < 4; ++nf)
                acc[mf][nf] = __builtin_amdgcn_mfma_f32_16x16x32_f16(af[mf], bf[nf], acc[mf][nf], 0, 0, 0);
    }
    // bias preload: lane's o rows are wm*64 + mf*16 + quad*4 + r
    float bv_[4][4];
#pragma unroll
    for (int mf = 0; mf < 4; ++mf)
#pragma unroll
        for (int r = 0; r < 4; ++r)
            bv_[mf][r] = bp[m0 + wm * 64 + mf * 16 + quad * 4 + r];
    // Epilogue: bounce to LDS as [l][o] fp16, store coalesced rows of Y[b][l][o']
#pragma unroll
    for (int pass = 0; pass < 2; ++pass) {
        __syncthreads();
        if (wm == pass) {
#pragma unroll
            for (int mf = 0; mf < 4; ++mf)
#pragma unroll
                for (int nf = 0; nf < 4; ++nf) {
                    const int olocal = mf * 16 + quad * 4;
                    const int llocal = wn * 64 + nf * 16 + ln;
                    f16x4 w;
#pragma unroll
                    for (int r = 0; r < 4; ++r) w[r] = (f16)(acc[mf][nf][r] + bv_[mf][r]);
                    *(f16x4*)&Cb[llocal * 72 + olocal] = w;
                }
        }
        __syncthreads();
        const int l = tid >> 1, half = tid & 1;
        f16* yr = Y + ((size_t)(b * SEQL + l0 + l)) * 256 + m0 + pass * 64 + half * 32;
#pragma unroll
        for (int c = 0; c < 4; ++c)
            *(f16x8*)(yr + c * 8) = *(const f16x8*)&Cb[l * 72 + half * 32 + c * 8];
    }
}

// ---------------------------------------------------------------------------
// KV[b][h][qd][kd] = sum_l elu1(k'[l][kd]) * v'[l][qd];  ksum likewise.
// inputs fp16 [b][l][h*32+d].  grid (16 splits, 64 bh), 256 threads.
// ---------------------------------------------------------------------------
__global__ __launch_bounds__(256) void kv_kernel(
    const f16* __restrict__ kp, const f16* __restrict__ vp,
    float* __restrict__ KV, float* __restrict__ ksum) {
    const int bh = blockIdx.y;
    const int b = bh >> 3, h = bh & 7;
    const int lbase = blockIdx.x * (SEQL / 16);
    __shared__ float ks[64][33];
    __shared__ float vs[64][33];
    const int t = threadIdx.x;
    const int lrow = t >> 2, seg = t & 3;
    const int kd = t & 31, qg = t >> 5;
    float a0 = 0.f, a1 = 0.f, a2 = 0.f, a3 = 0.f, ss = 0.f;
    for (int lc = 0; lc < SEQL / 16; lc += 64) {
        __syncthreads();
        const size_t off = ((size_t)(b * SEQL + lbase + lc + lrow)) * 256 + h * 32 + seg * 8;
        f16x8 k8 = *(const f16x8*)(kp + off);
        f16x8 v8 = *(const f16x8*)(vp + off);
#pragma unroll
        for (int j = 0; j < 8; ++j) {
            ks[lrow][seg * 8 + j] = elu1((float)k8[j]);
            vs[lrow][seg * 8 + j] = (float)v8[j];
        }
        __syncthreads();
#pragma unroll 8
        for (int li = 0; li < 64; ++li) {
            const float kk = ks[li][kd];
            ss += kk;
            a0 += kk * vs[li][qg * 4 + 0];
            a1 += kk * vs[li][qg * 4 + 1];
            a2 += kk * vs[li][qg * 4 + 2];
            a3 += kk * vs[li][qg * 4 + 3];
        }
    }
    float* KVb = KV + (size_t)(b * NHEADS + h) * HDIM * HDIM;
    atomicAdd(&KVb[(qg * 4 + 0) * HDIM + kd], a0);
    atomicAdd(&KVb[(qg * 4 + 1) * HDIM + kd], a1);
    atomicAdd(&KVb[(qg * 4 + 2) * HDIM + kd], a2);
    atomicAdd(&KVb[(qg * 4 + 3) * HDIM + kd], a3);
    if (qg == 0) atomicAdd(&ksum[(size_t)(b * NHEADS + h) * HDIM + kd], ss);
}

// ---------------------------------------------------------------------------
// attn: x[b][l][o'=h*32+qd] = q'.KV / (q'.ksum + eps); q fp16 in, x fp16 out.
// grid (64 l-tiles, 8 b), 256 threads; thread t owns channel o'=t.
// ---------------------------------------------------------------------------
__global__ __launch_bounds__(256) void attn_kernel(
    const f16* __restrict__ qp, const float* __restrict__ KV,
    const float* __restrict__ ksum, f16* __restrict__ xout) {
    const int b = blockIdx.y;
    const int l0 = blockIdx.x * 64;
    __shared__ float qls[64][260];
    const int t = threadIdx.x;
    const int h = t >> 5, qd = t & 31;
    float kvr[HDIM], ksr[HDIM];
    {
        const float* kvp = KV + ((size_t)(b * NHEADS + h) * HDIM + qd) * HDIM;
        const float* ksp = ksum + (size_t)(b * NHEADS + h) * HDIM;
#pragma unroll
        for (int i = 0; i < HDIM; i += 4) {
            float4 a = *(const float4*)(kvp + i);
            kvr[i] = a.x; kvr[i + 1] = a.y; kvr[i + 2] = a.z; kvr[i + 3] = a.w;
            float4 s = *(const float4*)(ksp + i);
            ksr[i] = s.x; ksr[i + 1] = s.y; ksr[i + 2] = s.z; ksr[i + 3] = s.w;
        }
    }
    const int lrow = t >> 2, c0 = (t & 3) * 64;
    {
        const f16* qr = qp + ((size_t)(b * SEQL + l0 + lrow)) * 256 + c0;
#pragma unroll
        for (int u = 0; u < 64; u += 8) {
            f16x8 v = *(const f16x8*)(qr + u);
#pragma unroll
            for (int j = 0; j < 8; ++j) qls[lrow][c0 + u + j] = elu1((float)v[j]);
        }
    }
    __syncthreads();
    for (int g = 0; g < 64; g += 8) {
        float num[8] = {}, den[8] = {};
#pragma unroll
        for (int kd = 0; kd < HDIM; ++kd) {
            const float kvv = kvr[kd], ksv = ksr[kd];
#pragma unroll
            for (int j = 0; j < 8; ++j) {
                const float qk = qls[g + j][h * 32 + kd];
                num[j] += qk * kvv;
                den[j] += qk * ksv;
            }
        }
        __syncthreads();
#pragma unroll
        for (int j = 0; j < 8; ++j) qls[g + j][t] = num[j] / (den[j] + EPS);
    }
    __syncthreads();
    {
        f16* xr = xout + ((size_t)(b * SEQL + l0 + lrow)) * 256 + c0;
#pragma unroll
        for (int u = 0; u < 64; u += 8) {
            f16x8 v;
#pragma unroll
            for (int j = 0; j < 8; ++j) v[j] = (f16)qls[lrow][c0 + u + j];
            *(f16x8*)(xr + u) = v;
        }
    }
}

// ---------------------------------------------------------------------------
// Wm GEMM: out[b][o][l] = sum_i' Wm16[o][i'] * x[b][l][i'] + bm[o]  (fp32 out)
// Both A and B tiles via global_load_lds (x already fp16, k-contiguous).
// ---------------------------------------------------------------------------
__global__ __launch_bounds__(256) void gemm_out(
    const f16* __restrict__ wm16, const f16* __restrict__ xt,
    const float* __restrict__ bm, float* __restrict__ out) {
    __shared__ __align__(16) f16 As[128 * 32];
    __shared__ __align__(16) f16 Bs[128 * 32];
    const int b = blockIdx.z;
    const int l0 = blockIdx.x * 128;
    const int m0 = blockIdx.y * 128;
    const int tid = threadIdx.x;
    const int wave = tid >> 6, lane = tid & 63;
    const int wm = wave >> 1, wn = wave & 1;
    const int ln = lane & 15, quad = lane >> 4;

    f32x4 acc[4][4];
#pragma unroll
    for (int mf = 0; mf < 4; ++mf)
#pragma unroll
        for (int nf = 0; nf < 4; ++nf)
#pragma unroll
            for (int r = 0; r < 4; ++r) acc[mf][nf][r] = 0.f;

    for (int k0 = 0; k0 < D_MODEL; k0 += 32) {
        __syncthreads();
#pragma unroll
        for (int iss = 0; iss < 2; ++iss) {
            const int row = wave * 32 + iss * 16 + (lane >> 2);
            const f16* gp = wm16 + (size_t)(m0 + row) * 256 + k0 + (lane & 3) * 8;
            gload_lds16(gp, As + (wave * 32 + iss * 16) * 32);
            const f16* gb = xt + ((size_t)(b * SEQL + l0 + row)) * 256 + k0 + (lane & 3) * 8;
            gload_lds16(gb, Bs + (wave * 32 + iss * 16) * 32);
        }
        __syncthreads();
        f16x8 af[4], bf[4];
#pragma unroll
        for (int mf = 0; mf < 4; ++mf)
            af[mf] = *(const f16x8*)&As[(wm * 64 + mf * 16 + ln) * 32 + quad * 8];
#pragma unroll
        for (int nf = 0; nf < 4; ++nf)
            bf[nf] = *(const f16x8*)&Bs[(wn * 64 + nf * 16 + ln) * 32 + quad * 8];
#pragma unroll
        for (int mf = 0; mf < 4; ++mf)
#pragma unroll
            for (int nf = 0; nf < 4; ++nf)
                acc[mf][nf] = __builtin_amdgcn_mfma_f32_16x16x32_f16(af[mf], bf[nf], acc[mf][nf], 0, 0, 0);
    }
    float bv_[4][4];
#pragma unroll
    for (int mf = 0; mf < 4; ++mf)
#pragma unroll
        for (int r = 0; r < 4; ++r)
            bv_[mf][r] = bm[m0 + wm * 64 + mf * 16 + quad * 4 + r];
#pragma unroll
    for (int mf = 0; mf < 4; ++mf) {
        const int o = m0 + wm * 64 + mf * 16 + quad * 4;
#pragma unroll
        for (int nf = 0; nf < 4; ++nf) {
            const int l = l0 + wn * 64 + nf * 16 + ln;
            float* op = out + ((size_t)(b * D_MODEL + o)) * SEQL + l;
#pragma unroll
            for (int r = 0; r < 4; ++r) op[(size_t)r * SEQL] = acc[mf][nf][r] + bv_[mf][r];
        }
    }
}

// ---------------------------------------------------------------------------
extern "C" void kernel_launch(void* const* d_in, const int* in_sizes, int n_in,
                              void* d_out, int out_size, void* d_ws, size_t ws_size,
                              hipStream_t stream) {
    const float* query = (const float*)d_in[0];
    const float* key_  = (const float*)d_in[1];
    const float* value = (const float*)d_in[2];
    const float* Wq = (const float*)d_in[3];
    const float* bq = (const float*)d_in[4];
    const float* Wk = (const float*)d_in[5];
    const float* bk = (const float*)d_in[6];
    const float* Wv = (const float*)d_in[7];
    const float* bv = (const float*)d_in[8];
    const float* Wm = (const float*)d_in[9];
    const float* bm = (const float*)d_in[10];

    char* w = (char*)d_ws;
    f16*   w16   = (f16*)w;                       // 4*65536 halves = 512 KB
    float* bperm = (float*)(w + 524288);          // 768 floats
    float* KV    = (float*)(w + 528384);          // 65536 floats
    float* ksum  = (float*)(w + 790528);          // 2048 floats
    f16*   qp    = (f16*)(w + 802816);
    f16*   kp    = qp + (size_t)BATCH * SEQL * 256;
    f16*   vp    = kp + (size_t)BATCH * SEQL * 256;
    f16*   xt    = kp;  // kp dead after kv_kernel

    prep_kernel<<<1025, 256, 0, stream>>>(Wq, Wk, Wv, Wm, bq, bk, bv, w16, bperm);
    zero_kernel<<<(65536 + 2048 + 255) / 256, 256, 0, stream>>>(KV, 65536 + 2048);

    gemm_stage1<<<dim3(SEQL / 128, 2, 24), 256, 0, stream>>>(
        query, key_, value, w16, bperm, qp, kp, vp);

    kv_kernel<<<dim3(16, BATCH * NHEADS), 256, 0, stream>>>(kp, vp, KV, ksum);

    attn_kernel<<<dim3(SEQL / 64, BATCH), 256, 0, stream>>>(qp, KV, ksum, xt);

    gemm_out<<<dim3(SEQL / 128, 2, BATCH), 256, 0, stream>>>(
        w16 + 3 * 65536, xt, bm, (float*)d_out);
}

// Round 3
// 233.260 us; speedup vs baseline: 1.8081x; 1.0774x over previous
//
#include <hip/hip_runtime.h>
#include <math.h>

#define D_MODEL 256
#define NHEADS 8
#define HDIM 32
#define BATCH 8
#define SEQL 4096
#define EPS 1e-6f

typedef _Float16 f16;
typedef _Float16 f16x4 __attribute__((ext_vector_type(4)));
typedef _Float16 f16x8 __attribute__((ext_vector_type(8)));
typedef float f32x4 __attribute__((ext_vector_type(4)));

__device__ __forceinline__ float elu1(float x) {
    return x > 0.f ? x + 1.f : __expf(x);
}

// ---------------------------------------------------------------------------
// prep: convert 4 weight mats to fp16.  Stage-1 weights row-permuted to
// head-major output channels (o' = h*32+kd <- o = kd*8+h); Wm column-permuted
// to accept head-major input.  Stage-1 biases permuted (fp32).
// ---------------------------------------------------------------------------
__global__ void prep_kernel(const float* __restrict__ Wq, const float* __restrict__ Wk,
                            const float* __restrict__ Wv, const float* __restrict__ Wm,
                            const float* __restrict__ bq, const float* __restrict__ bk,
                            const float* __restrict__ bv,
                            f16* __restrict__ w16, float* __restrict__ bperm) {
    if (blockIdx.x < 1024) {
        int idx = blockIdx.x * 256 + threadIdx.x;
        int mat = idx >> 16, r = (idx >> 8) & 255, c = idx & 255;
        const float* W = (mat == 0) ? Wq : (mat == 1) ? Wk : (mat == 2) ? Wv : Wm;
        float v;
        if (mat < 3) v = W[(size_t)(((r & 31) << 3) + (r >> 5)) * 256 + c];
        else         v = W[(size_t)r * 256 + (((c & 31) << 3) + (c >> 5))];
        w16[idx] = (f16)v;
    } else {
        int t = threadIdx.x;
        bperm[0 * 256 + t] = bq[((t & 31) << 3) + (t >> 5)];
        bperm[1 * 256 + t] = bk[((t & 31) << 3) + (t >> 5)];
        bperm[2 * 256 + t] = bv[((t & 31) << 3) + (t >> 5)];
    }
}

__global__ void zero_kernel(float* __restrict__ p, int n) {
    int i = blockIdx.x * blockDim.x + threadIdx.x;
    if (i < n) p[i] = 0.f;
}

// ---------------------------------------------------------------------------
// Stage-1 GEMM: Y[b][l][o'] = fp16( sum_i W16[o'][i] * X[b][i][l] + bperm[o'] )
// A-fragments loaded DIRECTLY from global (W is L2-hot, 128KB/matrix) -> no
// As staging, no global_load_lds, LDS = Bs only.  launch_bounds(256,4) to
// cap total regs <=128 (acc 64 + frags + staging) -> 4 blocks/CU.
// ---------------------------------------------------------------------------
#define BSTR 40  // Bs row stride in halves: 16B-aligned rows, ~2-way banks
__global__ __launch_bounds__(256, 4) void gemm_stage1(
    const float* __restrict__ Xq, const float* __restrict__ Xk, const float* __restrict__ Xv,
    const f16* __restrict__ w16, const float* __restrict__ bperm,
    f16* __restrict__ yq, f16* __restrict__ yk, f16* __restrict__ yv) {
    __shared__ __align__(16) char smem[18432];
    f16* Bs = (f16*)smem;            // [128][BSTR] = 10240 B
    f16* Cb = (f16*)smem;            // [128][72] epilogue bounce (aliases Bs)

    const int z = blockIdx.z;
    const int which = z >> 3;
    const int b = z & 7;
    const float* X = (which == 0) ? Xq : (which == 1) ? Xk : Xv;
    const f16* W = w16 + which * 65536;
    f16* Y = (which == 0) ? yq : (which == 1) ? yk : yv;
    const float* bp = bperm + which * 256;

    const int l0 = blockIdx.x * 128;
    const int m0 = blockIdx.y * 128;
    const int tid = threadIdx.x;
    const int wave = tid >> 6, lane = tid & 63;
    const int wm = wave >> 1, wn = wave & 1;
    const int ln = lane & 15, quad = lane >> 4;
    const int bp8 = tid & 7;    // i-quad: i_local = 4*bp8 + r
    const int bg = tid >> 3;    // l-quad: l_local = 4*bg + j

    f32x4 acc[4][4];
#pragma unroll
    for (int mf = 0; mf < 4; ++mf)
#pragma unroll
        for (int nf = 0; nf < 4; ++nf)
#pragma unroll
            for (int r = 0; r < 4; ++r) acc[mf][nf][r] = 0.f;

    for (int k0 = 0; k0 < D_MODEL; k0 += 32) {
        __syncthreads();
        {   // B tile: X[k0+i][l0+l] fp32 -> transpose/convert -> Bs[l][i]
            const float* xb = X + ((size_t)b * D_MODEL + k0 + 4 * bp8) * SEQL + l0 + 4 * bg;
            float4 r0 = *(const float4*)(xb + 0 * SEQL);
            float4 r1 = *(const float4*)(xb + 1 * SEQL);
            float4 r2 = *(const float4*)(xb + 2 * SEQL);
            float4 r3 = *(const float4*)(xb + 3 * SEQL);
            f16x4 w;
            w[0] = (f16)r0.x; w[1] = (f16)r1.x; w[2] = (f16)r2.x; w[3] = (f16)r3.x;
            *(f16x4*)&Bs[(4 * bg + 0) * BSTR + 4 * bp8] = w;
            w[0] = (f16)r0.y; w[1] = (f16)r1.y; w[2] = (f16)r2.y; w[3] = (f16)r3.y;
            *(f16x4*)&Bs[(4 * bg + 1) * BSTR + 4 * bp8] = w;
            w[0] = (f16)r0.z; w[1] = (f16)r1.z; w[2] = (f16)r2.z; w[3] = (f16)r3.z;
            *(f16x4*)&Bs[(4 * bg + 2) * BSTR + 4 * bp8] = w;
            w[0] = (f16)r0.w; w[1] = (f16)r1.w; w[2] = (f16)r2.w; w[3] = (f16)r3.w;
            *(f16x4*)&Bs[(4 * bg + 3) * BSTR + 4 * bp8] = w;
        }
        __syncthreads();
        f16x8 af[4], bf[4];
#pragma unroll
        for (int mf = 0; mf < 4; ++mf)
            af[mf] = *(const f16x8*)(W + (size_t)(m0 + wm * 64 + mf * 16 + ln) * 256 + k0 + quad * 8);
#pragma unroll
        for (int nf = 0; nf < 4; ++nf)
            bf[nf] = *(const f16x8*)&Bs[(wn * 64 + nf * 16 + ln) * BSTR + quad * 8];
#pragma unroll
        for (int mf = 0; mf < 4; ++mf)
#pragma unroll
            for (int nf = 0; nf < 4; ++nf)
                acc[mf][nf] = __builtin_amdgcn_mfma_f32_16x16x32_f16(af[mf], bf[nf], acc[mf][nf], 0, 0, 0);
    }
    float bv_[4][4];
#pragma unroll
    for (int mf = 0; mf < 4; ++mf)
#pragma unroll
        for (int r = 0; r < 4; ++r)
            bv_[mf][r] = bp[m0 + wm * 64 + mf * 16 + quad * 4 + r];
    // Epilogue: bounce to LDS as [l][o] fp16, store coalesced rows of Y[b][l][o']
#pragma unroll
    for (int pass = 0; pass < 2; ++pass) {
        __syncthreads();
        if (wm == pass) {
#pragma unroll
            for (int mf = 0; mf < 4; ++mf)
#pragma unroll
                for (int nf = 0; nf < 4; ++nf) {
                    const int olocal = mf * 16 + quad * 4;
                    const int llocal = wn * 64 + nf * 16 + ln;
                    f16x4 w;
#pragma unroll
                    for (int r = 0; r < 4; ++r) w[r] = (f16)(acc[mf][nf][r] + bv_[mf][r]);
                    *(f16x4*)&Cb[llocal * 72 + olocal] = w;
                }
        }
        __syncthreads();
        const int l = tid >> 1, half = tid & 1;
        f16* yr = Y + ((size_t)(b * SEQL + l0 + l)) * 256 + m0 + pass * 64 + half * 32;
#pragma unroll
        for (int c = 0; c < 4; ++c)
            *(f16x8*)(yr + c * 8) = *(const f16x8*)&Cb[l * 72 + half * 32 + c * 8];
    }
}

// ---------------------------------------------------------------------------
// KV[b][h][qd][kd] = sum_l elu1(k'[l][kd]) * v'[l][qd];  ksum likewise.
// inputs fp16 [b][l][h*32+d].  grid (16 splits, 64 bh), 256 threads.
// ---------------------------------------------------------------------------
__global__ __launch_bounds__(256) void kv_kernel(
    const f16* __restrict__ kp, const f16* __restrict__ vp,
    float* __restrict__ KV, float* __restrict__ ksum) {
    const int bh = blockIdx.y;
    const int b = bh >> 3, h = bh & 7;
    const int lbase = blockIdx.x * (SEQL / 16);
    __shared__ float ks[64][33];
    __shared__ float vs[64][33];
    const int t = threadIdx.x;
    const int lrow = t >> 2, seg = t & 3;
    const int kd = t & 31, qg = t >> 5;
    float a0 = 0.f, a1 = 0.f, a2 = 0.f, a3 = 0.f, ss = 0.f;
    for (int lc = 0; lc < SEQL / 16; lc += 64) {
        __syncthreads();
        const size_t off = ((size_t)(b * SEQL + lbase + lc + lrow)) * 256 + h * 32 + seg * 8;
        f16x8 k8 = *(const f16x8*)(kp + off);
        f16x8 v8 = *(const f16x8*)(vp + off);
#pragma unroll
        for (int j = 0; j < 8; ++j) {
            ks[lrow][seg * 8 + j] = elu1((float)k8[j]);
            vs[lrow][seg * 8 + j] = (float)v8[j];
        }
        __syncthreads();
#pragma unroll 8
        for (int li = 0; li < 64; ++li) {
            const float kk = ks[li][kd];
            ss += kk;
            a0 += kk * vs[li][qg * 4 + 0];
            a1 += kk * vs[li][qg * 4 + 1];
            a2 += kk * vs[li][qg * 4 + 2];
            a3 += kk * vs[li][qg * 4 + 3];
        }
    }
    float* KVb = KV + (size_t)(b * NHEADS + h) * HDIM * HDIM;
    atomicAdd(&KVb[(qg * 4 + 0) * HDIM + kd], a0);
    atomicAdd(&KVb[(qg * 4 + 1) * HDIM + kd], a1);
    atomicAdd(&KVb[(qg * 4 + 2) * HDIM + kd], a2);
    atomicAdd(&KVb[(qg * 4 + 3) * HDIM + kd], a3);
    if (qg == 0) atomicAdd(&ksum[(size_t)(b * NHEADS + h) * HDIM + kd], ss);
}

// ---------------------------------------------------------------------------
// Fused attention + output projection.
// Per block: 64-l tile, one batch.
//  phase0: stage q'=elu1(q) fp16 into xs[64][264]; build Baug[h][48][40] fp16
//          (rows 0..31 = KV[h][qd][kd], row 32 = ksum; rows 33..47 unread-garbage
//           cols feeding unread C columns).
//  phase1: per wave (2 heads each): num/den via 16x16x32 MFMA (A=q' from xs,
//          B=Baug), den broadcast through dens[][], x = num/(den+eps) written
//          back into xs in place (each wave owns its heads' columns).
//  phase2: out[b][o][l] = Wm x + bm, Wm frags straight from global (L2-hot),
//          no barriers in K-loop.
// ---------------------------------------------------------------------------
__global__ __launch_bounds__(256) void attn_out_kernel(
    const f16* __restrict__ qp, const float* __restrict__ KV,
    const float* __restrict__ ksum, const f16* __restrict__ wm16,
    const float* __restrict__ bm, float* __restrict__ out) {
    __shared__ __align__(16) f16 xs[64 * 264];        // 33792 B
    __shared__ __align__(16) f16 Baug[8 * 48 * 40];   // 30720 B
    __shared__ float dens[8][64];                     // 2048 B
    const int b = blockIdx.y;
    const int l0 = blockIdx.x * 64;
    const int t = threadIdx.x;
    const int wave = t >> 6, lane = t & 63;
    const int ln = lane & 15, quad = lane >> 4;

    // phase0a: Baug build (KV fp32 -> fp16, row-per-(h,qd); row 32 = ksum)
    {
        const int h = t >> 5, qd = t & 31;
        const float* kvp = KV + ((size_t)(b * NHEADS + h) * HDIM + qd) * HDIM;
        f16* dst = &Baug[(h * 48 + qd) * 40];
#pragma unroll
        for (int i = 0; i < 32; i += 4) {
            float4 a = *(const float4*)(kvp + i);
            f16x4 w4;
            w4[0] = (f16)a.x; w4[1] = (f16)a.y; w4[2] = (f16)a.z; w4[3] = (f16)a.w;
            *(f16x4*)(dst + i) = w4;
        }
        Baug[(h * 48 + 32) * 40 + qd] = (f16)ksum[(size_t)(b * NHEADS + h) * HDIM + qd];
    }
    // phase0b: q' staging (row = t&63 so wave writes 64 distinct LDS rows)
    {
        const int row = t & 63, cg = t >> 6;
        const f16* qr = qp + ((size_t)(b * SEQL + l0 + row)) * 256 + cg * 64;
        f16* dst = &xs[row * 264 + cg * 64];
#pragma unroll
        for (int u = 0; u < 64; u += 8) {
            f16x8 v = *(const f16x8*)(qr + u);
            f16x8 w;
#pragma unroll
            for (int j = 0; j < 8; ++j) w[j] = (f16)elu1((float)v[j]);
            *(f16x8*)(dst + u) = w;
        }
    }
    __syncthreads();
    // phase1: per-head small GEMMs; x written in place over q'
#pragma unroll
    for (int hh = 0; hh < 2; ++hh) {
        const int h = wave * 2 + hh;
        f16x8 a_s[4], b_s[3];
#pragma unroll
        for (int mf = 0; mf < 4; ++mf)
            a_s[mf] = *(const f16x8*)&xs[(mf * 16 + ln) * 264 + h * 32 + quad * 8];
#pragma unroll
        for (int nf = 0; nf < 3; ++nf)
            b_s[nf] = *(const f16x8*)&Baug[(h * 48 + nf * 16 + ln) * 40 + quad * 8];
        f32x4 C[4][3];
#pragma unroll
        for (int mf = 0; mf < 4; ++mf)
#pragma unroll
            for (int nf = 0; nf < 3; ++nf) {
#pragma unroll
                for (int r = 0; r < 4; ++r) C[mf][nf][r] = 0.f;
                C[mf][nf] = __builtin_amdgcn_mfma_f32_16x16x32_f16(a_s[mf], b_s[nf], C[mf][nf], 0, 0, 0);
            }
        if (ln == 0) {
#pragma unroll
            for (int mf = 0; mf < 4; ++mf)
#pragma unroll
                for (int r = 0; r < 4; ++r)
                    dens[h][mf * 16 + quad * 4 + r] = C[mf][2][r];
        }
        __syncthreads();
#pragma unroll
        for (int mf = 0; mf < 4; ++mf)
#pragma unroll
            for (int r = 0; r < 4; ++r) {
                const int l = mf * 16 + quad * 4 + r;
                const float rd = __builtin_amdgcn_rcpf(dens[h][l] + EPS);
#pragma unroll
                for (int nf = 0; nf < 2; ++nf)
                    xs[l * 264 + h * 32 + nf * 16 + ln] = (f16)(C[mf][nf][r] * rd);
            }
        __syncthreads();
    }
    // phase2: main GEMM, A = Wm from global, B = xs
    f32x4 acc[4][4];
#pragma unroll
    for (int mf = 0; mf < 4; ++mf)
#pragma unroll
        for (int nf = 0; nf < 4; ++nf)
#pragma unroll
            for (int r = 0; r < 4; ++r) acc[mf][nf][r] = 0.f;
    for (int k0 = 0; k0 < D_MODEL; k0 += 32) {
        f16x8 af[4], bf[4];
#pragma unroll
        for (int mf = 0; mf < 4; ++mf)
            af[mf] = *(const f16x8*)(wm16 + (size_t)(wave * 64 + mf * 16 + ln) * 256 + k0 + quad * 8);
#pragma unroll
        for (int nf = 0; nf < 4; ++nf)
            bf[nf] = *(const f16x8*)&xs[(nf * 16 + ln) * 264 + k0 + quad * 8];
#pragma unroll
        for (int mf = 0; mf < 4; ++mf)
#pragma unroll
            for (int nf = 0; nf < 4; ++nf)
                acc[mf][nf] = __builtin_amdgcn_mfma_f32_16x16x32_f16(af[mf], bf[nf], acc[mf][nf], 0, 0, 0);
    }
#pragma unroll
    for (int mf = 0; mf < 4; ++mf) {
        const int o = wave * 64 + mf * 16 + quad * 4;
#pragma unroll
        for (int r = 0; r < 4; ++r) {
            const float bb = bm[o + r];
            float* op = out + ((size_t)(b * D_MODEL + o + r)) * SEQL + l0;
#pragma unroll
            for (int nf = 0; nf < 4; ++nf)
                op[nf * 16 + ln] = acc[mf][nf][r] + bb;
        }
    }
}

// ---------------------------------------------------------------------------
extern "C" void kernel_launch(void* const* d_in, const int* in_sizes, int n_in,
                              void* d_out, int out_size, void* d_ws, size_t ws_size,
                              hipStream_t stream) {
    const float* query = (const float*)d_in[0];
    const float* key_  = (const float*)d_in[1];
    const float* value = (const float*)d_in[2];
    const float* Wq = (const float*)d_in[3];
    const float* bq = (const float*)d_in[4];
    const float* Wk = (const float*)d_in[5];
    const float* bk = (const float*)d_in[6];
    const float* Wv = (const float*)d_in[7];
    const float* bv = (const float*)d_in[8];
    const float* Wm = (const float*)d_in[9];
    const float* bm = (const float*)d_in[10];

    char* w = (char*)d_ws;
    f16*   w16   = (f16*)w;                       // 4*65536 halves = 512 KB
    float* bperm = (float*)(w + 524288);          // 768 floats
    float* KV    = (float*)(w + 528384);          // 65536 floats
    float* ksum  = (float*)(w + 790528);          // 2048 floats
    f16*   qp    = (f16*)(w + 802816);
    f16*   kp    = qp + (size_t)BATCH * SEQL * 256;
    f16*   vp    = kp + (size_t)BATCH * SEQL * 256;

    prep_kernel<<<1025, 256, 0, stream>>>(Wq, Wk, Wv, Wm, bq, bk, bv, w16, bperm);
    zero_kernel<<<(65536 + 2048 + 255) / 256, 256, 0, stream>>>(KV, 65536 + 2048);

    gemm_stage1<<<dim3(SEQL / 128, 2, 24), 256, 0, stream>>>(
        query, key_, value, w16, bperm, qp, kp, vp);

    kv_kernel<<<dim3(16, BATCH * NHEADS), 256, 0, stream>>>(kp, vp, KV, ksum);

    attn_out_kernel<<<dim3(SEQL / 64, BATCH), 256, 0, stream>>>(
        qp, KV, ksum, w16 + 3 * 65536, bm, (float*)d_out);
}